// Round 10
// baseline (48.697 us; speedup 1.0000x reference)
//
#include <hip/hip_runtime.h>
#include <math.h>

// Bahdanau attention, fp32. B=4, TQ=TV=256, H=D=512, U=256.
// out = [context (4*256*512)] ++ [attn (4*256*256)]
//
// tanh(x) = 1 - 2/(e^{2x}+1); e^{2(q+v)} = e^{2q}*e^{2v}.
// proj_mfma: bf16 MFMA GEMMs -> Eq[q][u], EvT[u][vg] with exp2 epilogue.
// score_softmax v2: f2/pk-fma math, uniform (s_load) eq/vw operands,
//   8-deep dbuf EvT loads. *** NREP=8 measurement round: the score body
//   repeats 8x (idempotent) so the kernel surfaces in the top-5 profile
//   table above the 39us ws-poison fills -> exact duration + counters. ***
// context_gemm: unchanged.

typedef float f4 __attribute__((ext_vector_type(4)));
typedef float f2 __attribute__((ext_vector_type(2)));
typedef __attribute__((ext_vector_type(8))) short s8v;            // 8 bf16
typedef __attribute__((ext_vector_type(8))) unsigned short u8v;

#define B_    4
#define TQ_   256
#define TV_   256
#define D_    512
#define U_    256
#define KDIM  512          // H == D == 512
#define MROWS 1024         // B*TQ == B*TV
#define NREP  8            // measurement multiplier for score_softmax

#define C2LOG2E 2.8853900817779268f   // 2*log2(e)

// ws layout (floats): Eq [1024][256] at 0 | EvT [256][1024] at 262144
#define EQ_OFF  0
#define EVT_OFF 262144

#if __has_builtin(__builtin_amdgcn_exp2f)
#define EXP2F(x) __builtin_amdgcn_exp2f(x)
#else
#define EXP2F(x) exp2f(x)
#endif
#if __has_builtin(__builtin_amdgcn_rcpf)
#define RCPF(x) __builtin_amdgcn_rcpf(x)
#else
#define RCPF(x) (1.0f / (x))
#endif

__device__ __forceinline__ unsigned short f2bf(float f) {   // RNE f32->bf16
    union { float f; unsigned u; } v; v.f = f;
    return (unsigned short)((v.u + 0x7FFF + ((v.u >> 16) & 1)) >> 16);
}

// ---------------- bf16 MFMA projection GEMMs + exp2 epilogue (unchanged) ----
__global__ __launch_bounds__(256) void proj_mfma(
    const float* __restrict__ query, const float* __restrict__ values,
    const float* __restrict__ W1, const float* __restrict__ b1,
    const float* __restrict__ W2, const float* __restrict__ b2,
    float* __restrict__ ws)
{
    __shared__ unsigned short Al[2][64][40];
    __shared__ unsigned short Bl[2][64][40];

    const int tid  = threadIdx.x;
    const int proj = blockIdx.y;
    const int x    = blockIdx.x;

    int m0, n0;
    if (proj == 0) { m0 = (x >> 2) * 64; n0 = (x & 3) * 64; }
    else           { m0 = (x & 3) * 64;  n0 = (x >> 2) * 64; }

    const int sr = tid >> 2;          // staging row 0..63
    const int sk = (tid & 3) * 8;     // k-segment

    const float* dptr = (proj ? values + (size_t)(n0 + sr) * KDIM
                              : query  + (size_t)(m0 + sr) * KDIM) + sk;
    const float* tptr = (proj ? W2 + (m0 + sr) : W1 + (n0 + sr))
                        + (size_t)sk * U_;

    f4 d0, d1;
    float tv0, tv1, tv2, tv3, tv4, tv5, tv6, tv7;

#define LOADR(S)                                                        \
    do {                                                                \
        const float* dp = dptr + (size_t)(S) * 32;                      \
        d0 = *(const f4*)(dp);                                          \
        d1 = *(const f4*)(dp + 4);                                      \
        const float* tp = tptr + (size_t)(S) * 32 * U_;                 \
        tv0 = tp[0];       tv1 = tp[U_];       tv2 = tp[2 * U_];        \
        tv3 = tp[3 * U_];  tv4 = tp[4 * U_];   tv5 = tp[5 * U_];        \
        tv6 = tp[6 * U_];  tv7 = tp[7 * U_];                            \
    } while (0)

#define WRITEB(BUF)                                                     \
    do {                                                                \
        u8v dd, tt;                                                     \
        dd[0] = f2bf(d0[0]); dd[1] = f2bf(d0[1]);                       \
        dd[2] = f2bf(d0[2]); dd[3] = f2bf(d0[3]);                       \
        dd[4] = f2bf(d1[0]); dd[5] = f2bf(d1[1]);                       \
        dd[6] = f2bf(d1[2]); dd[7] = f2bf(d1[3]);                       \
        tt[0] = f2bf(tv0); tt[1] = f2bf(tv1); tt[2] = f2bf(tv2);        \
        tt[3] = f2bf(tv3); tt[4] = f2bf(tv4); tt[5] = f2bf(tv5);        \
        tt[6] = f2bf(tv6); tt[7] = f2bf(tv7);                           \
        unsigned short* ddst = proj ? &Bl[BUF][sr][sk] : &Al[BUF][sr][sk]; \
        unsigned short* tdst = proj ? &Al[BUF][sr][sk] : &Bl[BUF][sr][sk]; \
        *(u8v*)ddst = dd;                                               \
        *(u8v*)tdst = tt;                                               \
    } while (0)

    f4 acc0 = {}, acc1 = {}, acc2 = {}, acc3 = {};

    const int w  = tid >> 6;          // wave 0..3 -> rows w*16..+15
    const int l  = tid & 63;
    const int fr = l & 15;
    const int fk = (l >> 4) * 8;

    LOADR(0);
    WRITEB(0);

    for (int s = 0; s < 16; ++s) {
        __syncthreads();
        if (s + 1 < 16) LOADR(s + 1);
        {
            const int bu = s & 1;
            s8v af  = *(const s8v*)&Al[bu][w * 16 + fr][fk];
            s8v bf0 = *(const s8v*)&Bl[bu][fr][fk];
            s8v bf1 = *(const s8v*)&Bl[bu][16 + fr][fk];
            s8v bf2 = *(const s8v*)&Bl[bu][32 + fr][fk];
            s8v bf3 = *(const s8v*)&Bl[bu][48 + fr][fk];
            acc0 = __builtin_amdgcn_mfma_f32_16x16x32_bf16(af, bf0, acc0, 0, 0, 0);
            acc1 = __builtin_amdgcn_mfma_f32_16x16x32_bf16(af, bf1, acc1, 0, 0, 0);
            acc2 = __builtin_amdgcn_mfma_f32_16x16x32_bf16(af, bf2, acc2, 0, 0, 0);
            acc3 = __builtin_amdgcn_mfma_f32_16x16x32_bf16(af, bf3, acc3, 0, 0, 0);
        }
        if (s + 1 < 16) WRITEB((s + 1) & 1);
    }
#undef LOADR
#undef WRITEB

    const int orow  = m0 + w * 16 + (l >> 4) * 4;
    const int ocol0 = n0 + (l & 15);

    if (proj == 0) {
        float* E = ws + EQ_OFF;       // Eq[1024][256]
        #pragma unroll
        for (int nt = 0; nt < 4; ++nt) {
            const int n = ocol0 + nt * 16;
            const float bias = b1[n];
            const f4 a = nt == 0 ? acc0 : nt == 1 ? acc1 : nt == 2 ? acc2 : acc3;
            #pragma unroll
            for (int r = 0; r < 4; ++r)
                E[(size_t)(orow + r) * U_ + n] =
                    EXP2F((a[r] + bias) * C2LOG2E);
        }
    } else {
        float* E = ws + EVT_OFF;      // EvT[256][1024]
        #pragma unroll
        for (int nt = 0; nt < 4; ++nt) {
            const int n = ocol0 + nt * 16;
            const f4 a = nt == 0 ? acc0 : nt == 1 ? acc1 : nt == 2 ? acc2 : acc3;
            #pragma unroll
            for (int r = 0; r < 4; ++r)
                E[(size_t)(orow + r) * MROWS + n] =
                    EXP2F((a[r] + b2[orow + r]) * C2LOG2E);
        }
    }
}

// ---------------- score + softmax v2 ----------------
// Block = (b, 2 q-rows), 256 threads. Thread owns v = tid.
// eq/vw via block-UNIFORM global loads (-> s_load, scalar pipe);
// q-pair math in f2 (-> v_pk_fma_f32); EvT 8-deep dbuf vector loads.
// NREP: whole body repeats (idempotent) for profile visibility.
__global__ __launch_bounds__(256) void score_softmax(
    const float* __restrict__ Vw, const float* __restrict__ ws,
    float* __restrict__ out)
{
    __shared__ float redmin[4][2];
    __shared__ float redsum[4][2];

    const int tid = threadIdx.x;
    const int b  = blockIdx.y;
    const int q0 = blockIdx.x * 2;

    const float* eq0 = ws + EQ_OFF + (size_t)(b * TQ_ + q0) * U_;   // uniform
    const float* eq1 = eq0 + U_;                                    // uniform
    const float* evp = ws + EVT_OFF + (size_t)b * TV_ + tid;        // per-lane
    float* attn = out + (size_t)B_ * TQ_ * D_ + (size_t)(b * TQ_ + q0) * TV_;

    #pragma unroll 1
    for (int rep = 0; rep < NREP; ++rep) {
        float evA[8], evB[8];
        #pragma unroll
        for (int i = 0; i < 8; ++i) evA[i] = evp[(size_t)i * MROWS];

        f2 p = {0.f, 0.f};
        const f2 one = {1.0f, 1.0f};

#define SGRP(BUF, G)                                                    \
        _Pragma("unroll")                                               \
        for (int i = 0; i < 8; ++i) {                                   \
            const int u = (G) * 8 + i;                                  \
            f2 eq = {eq0[u], eq1[u]};      /* s_load pair */            \
            f2 ev2 = {BUF[i], BUF[i]};                                  \
            f2 den = eq * ev2 + one;       /* v_pk_fma_f32 */           \
            f2 r = {RCPF(den.x), RCPF(den.y)};                          \
            f2 wv = {Vw[u], Vw[u]};        /* s_load */                 \
            p = wv * r + p;                /* v_pk_fma_f32 */           \
        }

        #pragma unroll
        for (int g = 0; g < 32; g += 2) {
            #pragma unroll
            for (int i = 0; i < 8; ++i)
                evB[i] = evp[(size_t)((g + 1) * 8 + i) * MROWS];
            SGRP(evA, g)
            if (g + 2 < 32) {
                #pragma unroll
                for (int i = 0; i < 8; ++i)
                    evA[i] = evp[(size_t)((g + 2) * 8 + i) * MROWS];
            }
            SGRP(evB, g + 1)
        }
#undef SGRP

        // softmax over v (score = const - 2p: max score = min p)
        const int w = tid >> 6, lane = tid & 63;
        float m0 = p.x, m1 = p.y;
        #pragma unroll
        for (int off = 32; off; off >>= 1) {
            m0 = fminf(m0, __shfl_xor(m0, off));
            m1 = fminf(m1, __shfl_xor(m1, off));
        }
        if (lane == 0) { redmin[w][0] = m0; redmin[w][1] = m1; }
        __syncthreads();
        m0 = fminf(fminf(redmin[0][0], redmin[1][0]),
                   fminf(redmin[2][0], redmin[3][0]));
        m1 = fminf(fminf(redmin[0][1], redmin[1][1]),
                   fminf(redmin[2][1], redmin[3][1]));

        float e0 = EXP2F((m0 - p.x) * C2LOG2E);
        float e1 = EXP2F((m1 - p.y) * C2LOG2E);

        float s0 = e0, s1 = e1;
        #pragma unroll
        for (int off = 32; off; off >>= 1) {
            s0 += __shfl_xor(s0, off);
            s1 += __shfl_xor(s1, off);
        }
        if (lane == 0) { redsum[w][0] = s0; redsum[w][1] = s1; }
        __syncthreads();
        s0 = redsum[0][0] + redsum[1][0] + redsum[2][0] + redsum[3][0];
        s1 = redsum[0][1] + redsum[1][1] + redsum[2][1] + redsum[3][1];

        attn[tid]       = e0 * (1.0f / s0);   // exact division
        attn[TV_ + tid] = e1 * (1.0f / s1);

        __syncthreads();                  // reps fully ordered
        asm volatile("" ::: "memory");    // defeat cross-rep CSE of loads
    }
}

// ---------------- context: attn @ values (unchanged from R8) ----------------
__global__ __launch_bounds__(256) void context_gemm(
    const float* __restrict__ values, float* __restrict__ out)
{
    __shared__ __align__(16) f4 apk[TV_];

    const int tid = threadIdx.x;
    const int b  = blockIdx.y;
    const int q0 = blockIdx.x * 4;

    const float* at = out + (size_t)B_ * TQ_ * D_ + (size_t)(b * TQ_ + q0) * TV_;
    apk[tid] = f4{at[tid], at[TV_ + tid], at[2 * TV_ + tid], at[3 * TV_ + tid]};

    const f2* vp = (const f2*)(values + (size_t)b * TV_ * D_) + tid;

    f2 bufA[8], bufB[8];
    #pragma unroll
    for (int i = 0; i < 8; ++i) bufA[i] = vp[(size_t)i * (D_ / 2)];

    __syncthreads();

    f2 acc0 = {0.f, 0.f}, acc1 = {0.f, 0.f}, acc2 = {0.f, 0.f}, acc3 = {0.f, 0.f};

    #define CGRP(BUF, G)                                                 \
        _Pragma("unroll")                                                \
        for (int i = 0; i < 8; ++i) {                                    \
            f4 a = apk[(G) * 8 + i];                                     \
            f2 val = BUF[i];                                             \
            acc0 += a.x * val;                                           \
            acc1 += a.y * val;                                           \
            acc2 += a.z * val;                                           \
            acc3 += a.w * val;                                           \
        }

    #pragma unroll
    for (int g = 0; g < 32; g += 2) {
        #pragma unroll
        for (int i = 0; i < 8; ++i)
            bufB[i] = vp[(size_t)((g + 1) * 8 + i) * (D_ / 2)];
        CGRP(bufA, g)
        if (g + 2 < 32) {
            #pragma unroll
            for (int i = 0; i < 8; ++i)
                bufA[i] = vp[(size_t)((g + 2) * 8 + i) * (D_ / 2)];
        }
        CGRP(bufB, g + 1)
    }
    #undef CGRP

    float* orow = out + (size_t)(b * TQ_ + q0) * D_ + 2 * tid;
    *(f2*)(orow)          = acc0;
    *(f2*)(orow + D_)     = acc1;
    *(f2*)(orow + 2 * D_) = acc2;
    *(f2*)(orow + 3 * D_) = acc3;
}

extern "C" void kernel_launch(void* const* d_in, const int* in_sizes, int n_in,
                              void* d_out, int out_size, void* d_ws, size_t ws_size,
                              hipStream_t stream) {
    const float* query  = (const float*)d_in[0];
    const float* values = (const float*)d_in[1];
    const float* W1     = (const float*)d_in[2];
    const float* b1     = (const float*)d_in[3];
    const float* W2     = (const float*)d_in[4];
    const float* b2     = (const float*)d_in[5];
    const float* Vw     = (const float*)d_in[6];
    float* out = (float*)d_out;
    float* ws  = (float*)d_ws;

    proj_mfma<<<dim3(64, 2), 256, 0, stream>>>(query, values, W1, b1, W2, b2, ws);
    score_softmax<<<dim3(TQ_ / 2, B_), 256, 0, stream>>>(Vw, ws, out);
    context_gemm<<<dim3(TQ_ / 4, B_), 256, 0, stream>>>(values, out);
}